// Round 1
// baseline (505.324 us; speedup 1.0000x reference)
//
#include <hip/hip_runtime.h>

// PAttention: y = softmax_band(x@Wq^T @ Pk^T * scale) @ Pv, window |l-t|<w.
// L=4096, T=4096, d=2048 fixed by in_sizes; w read from device scalar.
// Pipeline: K1 q=x·Wq^T (bf16 ws) -> K2 banded e=exp(q·Pk^T·scale) (bf16 ws)
//           + fp32 rowsums -> K3 y=(P·Pv)/rowsum.
// MFMA 16x16x32 bf16, verified layouts: A/B frag [idx=lane&15][k=(lane>>4)*8+j],
// C/D col=lane&15 row=(lane>>4)*4+reg.

using bf16x8 = __attribute__((ext_vector_type(8))) short;
using f32x4  = __attribute__((ext_vector_type(4))) float;

#define TDIM 4096
#define DDIM 2048

static __device__ __forceinline__ unsigned short f2bf(float f) {
  union { float f; unsigned u; } c; c.f = f;
  unsigned r = c.u + 0x7FFFu + ((c.u >> 16) & 1u);  // RNE
  return (unsigned short)(r >> 16);
}
static __device__ __forceinline__ unsigned pack2(float a, float b) {
  return (unsigned)f2bf(a) | ((unsigned)f2bf(b) << 16);
}

// ---------------- K1: C(MxN) bf16 = A(MxK) f32 · B(NxK)^T f32 ----------------
__global__ __launch_bounds__(256) void k_gemm_bt(const float* __restrict__ A,
                                                 const float* __restrict__ B,
                                                 unsigned short* __restrict__ C,
                                                 int M, int N, int K) {
  __shared__ __align__(16) unsigned short As[64][32];
  __shared__ __align__(16) unsigned short Bs[64][32];
  const int tid = threadIdx.x;
  const int wave = tid >> 6, lane = tid & 63;
  const int quad = lane >> 4, l16 = lane & 15;
  const int m0 = blockIdx.y * 64, n0 = blockIdx.x * 64;
  const int lr = tid >> 2, lc = (tid & 3) * 8;

  f32x4 acc[4] = {};
  const float* Ap = A + (long)(m0 + lr) * K + lc;
  const float* Bp = B + (long)(n0 + lr) * K + lc;

  for (int k0 = 0; k0 < K; k0 += 32) {
    float4 a0 = *(const float4*)(Ap + k0);
    float4 a1 = *(const float4*)(Ap + k0 + 4);
    float4 b0 = *(const float4*)(Bp + k0);
    float4 b1 = *(const float4*)(Bp + k0 + 4);
    uint4 wa = { pack2(a0.x, a0.y), pack2(a0.z, a0.w), pack2(a1.x, a1.y), pack2(a1.z, a1.w) };
    uint4 wb = { pack2(b0.x, b0.y), pack2(b0.z, b0.w), pack2(b1.x, b1.y), pack2(b1.z, b1.w) };
    *(uint4*)&As[lr][lc] = wa;
    *(uint4*)&Bs[lr][lc] = wb;
    __syncthreads();
    bf16x8 af = *(const bf16x8*)&As[wave * 16 + l16][quad * 8];
#pragma unroll
    for (int nt = 0; nt < 4; ++nt) {
      bf16x8 bfr = *(const bf16x8*)&Bs[nt * 16 + l16][quad * 8];
      acc[nt] = __builtin_amdgcn_mfma_f32_16x16x32_bf16(af, bfr, acc[nt], 0, 0, 0);
    }
    __syncthreads();
  }
#pragma unroll
  for (int nt = 0; nt < 4; ++nt)
#pragma unroll
    for (int r = 0; r < 4; ++r) {
      int row = m0 + wave * 16 + quad * 4 + r;
      int col = n0 + nt * 16 + l16;
      C[(long)row * N + col] = f2bf(acc[nt][r]);
    }
}

// ------------- K2: banded S = Q·Pk^T·scale, write e=exp(S) + rowsums -------------
__global__ __launch_bounds__(256) void k_qk_exp(const unsigned short* __restrict__ Q,
                                                const float* __restrict__ Kp,
                                                unsigned short* __restrict__ P,
                                                float* __restrict__ rowsum,
                                                const int* __restrict__ wptr) {
  __shared__ __align__(16) unsigned short As[64][32];
  __shared__ __align__(16) unsigned short Bs[64][32];
  const int w = *wptr;
  const int l0 = blockIdx.y * 64;
  const int t0 = blockIdx.x * 64;
  int lo_t = l0 - (w - 1); if (lo_t < 0) lo_t = 0;
  int hi_t = l0 + 63 + (w - 1); if (hi_t > TDIM - 1) hi_t = TDIM - 1;
  const int Jlo = lo_t >> 6, Jhi = hi_t >> 6;
  if ((int)blockIdx.x < Jlo || (int)blockIdx.x > Jhi) return;  // uniform exit

  const int tid = threadIdx.x;
  const int wave = tid >> 6, lane = tid & 63;
  const int quad = lane >> 4, l16 = lane & 15;
  const int lr = tid >> 2, lc = (tid & 3) * 8;

  f32x4 acc[4] = {};
  const unsigned short* Qp = Q + (long)(l0 + lr) * DDIM + lc;
  const float* Kpp = Kp + (long)(t0 + lr) * DDIM + lc;

  for (int k0 = 0; k0 < DDIM; k0 += 32) {
    uint4 wa = *(const uint4*)(Qp + k0);
    float4 b0 = *(const float4*)(Kpp + k0);
    float4 b1 = *(const float4*)(Kpp + k0 + 4);
    uint4 wb = { pack2(b0.x, b0.y), pack2(b0.z, b0.w), pack2(b1.x, b1.y), pack2(b1.z, b1.w) };
    *(uint4*)&As[lr][lc] = wa;
    *(uint4*)&Bs[lr][lc] = wb;
    __syncthreads();
    bf16x8 af = *(const bf16x8*)&As[wave * 16 + l16][quad * 8];
#pragma unroll
    for (int nt = 0; nt < 4; ++nt) {
      bf16x8 bfr = *(const bf16x8*)&Bs[nt * 16 + l16][quad * 8];
      acc[nt] = __builtin_amdgcn_mfma_f32_16x16x32_bf16(af, bfr, acc[nt], 0, 0, 0);
    }
    __syncthreads();
  }

  const float scale = 0.022097086912079608f;  // 1/sqrt(2048)
  float rs[4] = {0.f, 0.f, 0.f, 0.f};
#pragma unroll
  for (int nt = 0; nt < 4; ++nt) {
#pragma unroll
    for (int r = 0; r < 4; ++r) {
      const int l = l0 + wave * 16 + quad * 4 + r;
      const int t = t0 + nt * 16 + l16;
      int dlt = l - t; dlt = dlt < 0 ? -dlt : dlt;
      float e = 0.f;
      // scores ~ N(0,1): max |s| ~ 6 -> exp never overflows; max-free softmax
      if (dlt < w) e = __expf(acc[nt][r] * scale);
      unsigned short bv = f2bf(e);
      P[(long)l * TDIM + t] = bv;
      rs[r] += __uint_as_float((unsigned)bv << 16);  // sum the stored (rounded) value
    }
  }
#pragma unroll
  for (int r = 0; r < 4; ++r) {
    float s = rs[r];
    s += __shfl_xor(s, 1);
    s += __shfl_xor(s, 2);
    s += __shfl_xor(s, 4);
    s += __shfl_xor(s, 8);  // reduce over the 16 lanes holding this row
    if (l16 == 0) atomicAdd(&rowsum[l0 + wave * 16 + quad * 4 + r], s);
  }
}

// ---------------- K3: y = (P · Pv) / rowsum over band tiles ----------------
__global__ __launch_bounds__(256) void k_pv(const unsigned short* __restrict__ P,
                                            const float* __restrict__ V,
                                            const float* __restrict__ rowsum,
                                            float* __restrict__ Y,
                                            const int* __restrict__ wptr) {
  __shared__ __align__(16) unsigned short Ps[64][32];
  __shared__ __align__(16) unsigned short Vs[64][32];  // Vs[j_local][t_local] (transposed)
  const int w = *wptr;
  const int l0 = blockIdx.y * 64;
  const int j0 = blockIdx.x * 64;
  int lo_t = l0 - (w - 1); if (lo_t < 0) lo_t = 0;
  int hi_t = l0 + 63 + (w - 1); if (hi_t > TDIM - 1) hi_t = TDIM - 1;
  const int ktb = (lo_t >> 6) * 64;         // same tile range K2 wrote
  const int kte = ((hi_t >> 6) + 1) * 64;

  const int tid = threadIdx.x;
  const int wave = tid >> 6, lane = tid & 63;
  const int quad = lane >> 4, l16 = lane & 15;
  const int lr = tid >> 2, lc = (tid & 3) * 8;  // P staging
  const int tt = tid >> 3, jj = (tid & 7) * 8;  // V staging (transpose)

  f32x4 acc[4] = {};
  for (int t0 = ktb; t0 < kte; t0 += 32) {
    *(uint4*)&Ps[lr][lc] = *(const uint4*)(P + (long)(l0 + lr) * TDIM + t0 + lc);
    const float4* vp = (const float4*)(V + (long)(t0 + tt) * DDIM + j0 + jj);
    float4 v0 = vp[0], v1 = vp[1];
    Vs[jj + 0][tt] = f2bf(v0.x);
    Vs[jj + 1][tt] = f2bf(v0.y);
    Vs[jj + 2][tt] = f2bf(v0.z);
    Vs[jj + 3][tt] = f2bf(v0.w);
    Vs[jj + 4][tt] = f2bf(v1.x);
    Vs[jj + 5][tt] = f2bf(v1.y);
    Vs[jj + 6][tt] = f2bf(v1.z);
    Vs[jj + 7][tt] = f2bf(v1.w);
    __syncthreads();
    bf16x8 af = *(const bf16x8*)&Ps[wave * 16 + l16][quad * 8];
#pragma unroll
    for (int nt = 0; nt < 4; ++nt) {
      bf16x8 bfr = *(const bf16x8*)&Vs[nt * 16 + l16][quad * 8];
      acc[nt] = __builtin_amdgcn_mfma_f32_16x16x32_bf16(af, bfr, acc[nt], 0, 0, 0);
    }
    __syncthreads();
  }
#pragma unroll
  for (int r = 0; r < 4; ++r) {
    const int l = l0 + wave * 16 + quad * 4 + r;
    const float inv = 1.0f / rowsum[l];
#pragma unroll
    for (int nt = 0; nt < 4; ++nt) {
      Y[(long)l * DDIM + j0 + nt * 16 + l16] = acc[nt][r] * inv;
    }
  }
}

extern "C" void kernel_launch(void* const* d_in, const int* in_sizes, int n_in,
                              void* d_out, int out_size, void* d_ws, size_t ws_size,
                              hipStream_t stream) {
  const float* x  = (const float*)d_in[0];   // (4096, 2048)
  const float* Wq = (const float*)d_in[1];   // (2048, 2048)
  const float* Pk = (const float*)d_in[2];   // (1, 4096, 2048)
  const float* Pv = (const float*)d_in[3];   // (1, 4096, 2048)
  const int* wptr = (const int*)d_in[4];     // sliding_window_size
  float* Y = (float*)d_out;                  // (1, 4096, 2048) f32

  // ws layout: q bf16 16MB | P bf16 32MB | rowsum f32 16KB  (~48MB total)
  unsigned short* qw = (unsigned short*)d_ws;
  unsigned short* Pm = qw + (size_t)4096 * 2048;
  float* rowsum = (float*)(Pm + (size_t)TDIM * TDIM);

  hipMemsetAsync(rowsum, 0, 4096 * sizeof(float), stream);
  k_gemm_bt<<<dim3(2048 / 64, 4096 / 64), 256, 0, stream>>>(x, Wq, qw, 4096, 2048, 2048);
  k_qk_exp<<<dim3(TDIM / 64, 4096 / 64), 256, 0, stream>>>(qw, Pk, Pm, rowsum, wptr);
  k_pv<<<dim3(DDIM / 64, 4096 / 64), 256, 0, stream>>>(Pm, Pv, rowsum, Y, wptr);
}

// Round 2
// 318.999 us; speedup vs baseline: 1.5841x; 1.5841x over previous
//
#include <hip/hip_runtime.h>

// PAttention: y = softmax_band(x@Wq^T @ Pk^T * scale) @ Pv, window |l-t|<w.
// L=4096, T=4096, d=2048. Pipeline:
//   K0: convert x,Wq,Pk -> bf16; transpose+convert Pv -> Vt (d x T) bf16
//   K1: q = x·Wq^T          (m97-style 128x128 bf16 MFMA GEMM, global_load_lds)
//   K2: P = exp(q·Pk^T·scale) masked, + fp32 rowsums (band tiles only)
//   K3: y = (P·Vt^T)/rowsum  (band tiles only)
// MFMA 16x16x32 bf16 layouts (verified m89/m91): A/B frag [idx=lane&15][k=(lane>>4)*8+j],
// C/D col=lane&15, row=(lane>>4)*4+reg.

using bf16x8 = __attribute__((ext_vector_type(8))) short;
using f32x4  = __attribute__((ext_vector_type(4))) float;

#define LDIM 4096
#define TDIM 4096
#define DDIM 2048

static __device__ __forceinline__ unsigned short f2bf(float f) {
  union { float f; unsigned u; } c; c.f = f;
  unsigned r = c.u + 0x7FFFu + ((c.u >> 16) & 1u);  // RNE
  return (unsigned short)(r >> 16);
}
static __device__ __forceinline__ unsigned pack2(float a, float b) {
  return (unsigned)f2bf(a) | ((unsigned)f2bf(b) << 16);
}

static __device__ __forceinline__ void gload16(const void* g, void* l) {
  __builtin_amdgcn_global_load_lds((const __attribute__((address_space(1))) void*)g,
                                   (__attribute__((address_space(3))) void*)l, 16, 0, 0);
}

// ---------------- K0a: f32 -> bf16 elementwise (8 elems/thread) ----------------
__global__ __launch_bounds__(256) void k_cvt(const float* __restrict__ in,
                                             unsigned short* __restrict__ out, int n8) {
  int i = blockIdx.x * 256 + threadIdx.x;
  if (i >= n8) return;
  const float4* p = (const float4*)(in + (size_t)i * 8);
  float4 a = p[0], b = p[1];
  uint4 o = { pack2(a.x, a.y), pack2(a.z, a.w), pack2(b.x, b.y), pack2(b.z, b.w) };
  *(uint4*)(out + (size_t)i * 8) = o;
}

// ------------- K0b: Pv (T x D) f32 -> Vt (D x T) bf16, LDS 64x64 tile -------------
__global__ __launch_bounds__(256) void k_trans(const float* __restrict__ V,
                                               unsigned short* __restrict__ Vt) {
  __shared__ unsigned short tile[64][65];
  const int t0 = blockIdx.x * 64;
  const int j0 = blockIdx.y * 64;
  const int tid = threadIdx.x;
  const int r = tid >> 4;          // 0..15
  const int c = (tid & 15) * 4;    // 0..60
#pragma unroll
  for (int rr = 0; rr < 64; rr += 16) {
    float4 v = *(const float4*)(V + (size_t)(t0 + r + rr) * DDIM + j0 + c);
    tile[r + rr][c + 0] = f2bf(v.x);
    tile[r + rr][c + 1] = f2bf(v.y);
    tile[r + rr][c + 2] = f2bf(v.z);
    tile[r + rr][c + 3] = f2bf(v.w);
  }
  __syncthreads();
#pragma unroll
  for (int rr = 0; rr < 64; rr += 16) {
    ushort4 o = { tile[c + 0][r + rr], tile[c + 1][r + rr],
                  tile[c + 2][r + rr], tile[c + 3][r + rr] };
    *(ushort4*)(Vt + (size_t)(j0 + r + rr) * TDIM + t0 + c) = o;
  }
}

// ------------- shared 128x128 bf16 GEMM K-loop (A MxK, B NxK row-major) -------------
static __device__ __forceinline__ void gemm_loop(const unsigned short* __restrict__ A,
                                                 const unsigned short* __restrict__ B,
                                                 int m0, int n0, long lda, long ldb,
                                                 int kbeg, int kend,
                                                 unsigned short* As, unsigned short* Bs,
                                                 f32x4 (&acc)[4][4]) {
  const int tid = threadIdx.x;
  const int wave = tid >> 6, lane = tid & 63;
  const int quad = lane >> 4, l16 = lane & 15;
  const int wm = wave >> 1, wn = wave & 1;
  // staging: wave covers rows [wave*32, wave*32+32) of the 128x32 tile,
  // as two 1KB chunks (16 rows each); lane i -> row +i/4, col (i&3)*8.
  const int srow = wave * 32 + (lane >> 2);
  const int scol = (lane & 3) * 8;

  for (int k0 = kbeg; k0 < kend; k0 += 32) {
    const unsigned short* gA = A + (long)(m0 + srow) * lda + k0 + scol;
    const unsigned short* gB = B + (long)(n0 + srow) * ldb + k0 + scol;
    gload16(gA,            As + wave * 1024);
    gload16(gA + 16 * lda, As + wave * 1024 + 512);
    gload16(gB,            Bs + wave * 1024);
    gload16(gB + 16 * ldb, Bs + wave * 1024 + 512);
    __syncthreads();  // compiler emits vmcnt(0) drain before s_barrier
    bf16x8 af[4], bf[4];
#pragma unroll
    for (int i = 0; i < 4; i++)
      af[i] = *(const bf16x8*)&As[(wm * 64 + i * 16 + l16) * 32 + quad * 8];
#pragma unroll
    for (int i = 0; i < 4; i++)
      bf[i] = *(const bf16x8*)&Bs[(wn * 64 + i * 16 + l16) * 32 + quad * 8];
#pragma unroll
    for (int i = 0; i < 4; i++)
#pragma unroll
      for (int j = 0; j < 4; j++)
        acc[i][j] = __builtin_amdgcn_mfma_f32_16x16x32_bf16(af[i], bf[j], acc[i][j], 0, 0, 0);
    __syncthreads();
  }
}

// ---------------- K1: q = x · Wq^T  (bf16 out) ----------------
__global__ __launch_bounds__(256) void k1_qgemm(const unsigned short* __restrict__ X,
                                                const unsigned short* __restrict__ W,
                                                unsigned short* __restrict__ q) {
  __shared__ __align__(16) unsigned short As[128 * 32];
  __shared__ __align__(16) unsigned short Bs[128 * 32];
  f32x4 acc[4][4] = {};
  const int m0 = blockIdx.y * 128, n0 = blockIdx.x * 128;
  gemm_loop(X, W, m0, n0, DDIM, DDIM, 0, DDIM, As, Bs, acc);
  const int tid = threadIdx.x;
  const int wave = tid >> 6, lane = tid & 63;
  const int quad = lane >> 4, l16 = lane & 15, wm = wave >> 1, wn = wave & 1;
#pragma unroll
  for (int i = 0; i < 4; i++)
#pragma unroll
    for (int j = 0; j < 4; j++)
#pragma unroll
      for (int r = 0; r < 4; r++) {
        int row = m0 + wm * 64 + i * 16 + quad * 4 + r;
        int col = n0 + wn * 64 + j * 16 + l16;
        q[(long)row * DDIM + col] = f2bf(acc[i][j][r]);
      }
}

// ------------- K2: banded P = exp(q·Pk^T·scale), rowsums -------------
__global__ __launch_bounds__(256) void k2_qk(const unsigned short* __restrict__ Q,
                                             const unsigned short* __restrict__ Kb,
                                             unsigned short* __restrict__ P,
                                             float* __restrict__ rowsum,
                                             const int* __restrict__ wptr) {
  const int w = *wptr;
  const int l0 = blockIdx.y * 128, t0 = blockIdx.x * 128;
  int lo = l0 - w + 1; if (lo < 0) lo = 0;
  int hi = l0 + 127 + w - 1; if (hi > TDIM - 1) hi = TDIM - 1;
  if ((int)blockIdx.x < (lo >> 7) || (int)blockIdx.x > (hi >> 7)) return;  // uniform exit
  __shared__ __align__(16) unsigned short As[128 * 32];
  __shared__ __align__(16) unsigned short Bs[128 * 32];
  f32x4 acc[4][4] = {};
  gemm_loop(Q, Kb, l0, t0, DDIM, DDIM, 0, DDIM, As, Bs, acc);
  const float scale = 0.022097086912079608f;  // 1/sqrt(2048)
  const int tid = threadIdx.x;
  const int wave = tid >> 6, lane = tid & 63;
  const int quad = lane >> 4, l16 = lane & 15, wm = wave >> 1, wn = wave & 1;
#pragma unroll
  for (int i = 0; i < 4; i++) {
    float rs[4] = {0.f, 0.f, 0.f, 0.f};
#pragma unroll
    for (int j = 0; j < 4; j++)
#pragma unroll
      for (int r = 0; r < 4; r++) {
        int l = l0 + wm * 64 + i * 16 + quad * 4 + r;
        int t = t0 + wn * 64 + j * 16 + l16;
        int dlt = l - t; dlt = dlt < 0 ? -dlt : dlt;
        float e = 0.f;
        // scores ~ N(0,1): no overflow -> max-free softmax is exact math
        if (dlt < w) e = __expf(acc[i][j][r] * scale);
        unsigned short bv = f2bf(e);
        P[(long)l * TDIM + t] = bv;
        rs[r] += __uint_as_float((unsigned)bv << 16);  // sum stored (rounded) values
      }
#pragma unroll
    for (int r = 0; r < 4; ++r) {
      float s = rs[r];
      s += __shfl_xor(s, 1);
      s += __shfl_xor(s, 2);
      s += __shfl_xor(s, 4);
      s += __shfl_xor(s, 8);  // reduce over the 16 lanes of this row
      if (l16 == 0) atomicAdd(&rowsum[l0 + wm * 64 + i * 16 + quad * 4 + r], s);
    }
  }
}

// ---------------- K3: y = (P · Vt^T) / rowsum over band tiles ----------------
__global__ __launch_bounds__(256) void k3_pv(const unsigned short* __restrict__ P,
                                             const unsigned short* __restrict__ Vt,
                                             const float* __restrict__ rowsum,
                                             float* __restrict__ Y,
                                             const int* __restrict__ wptr) {
  const int w = *wptr;
  const int l0 = blockIdx.y * 128, j0 = blockIdx.x * 128;
  int lo = l0 - w + 1; if (lo < 0) lo = 0;
  int hi = l0 + 127 + w - 1; if (hi > TDIM - 1) hi = TDIM - 1;
  const int kb = (lo >> 7) * 128, ke = ((hi >> 7) + 1) * 128;  // exactly K2's tiles
  __shared__ __align__(16) unsigned short As[128 * 32];
  __shared__ __align__(16) unsigned short Bs[128 * 32];
  f32x4 acc[4][4] = {};
  gemm_loop(P, Vt, l0, j0, TDIM, TDIM, kb, ke, As, Bs, acc);
  const int tid = threadIdx.x;
  const int wave = tid >> 6, lane = tid & 63;
  const int quad = lane >> 4, l16 = lane & 15, wm = wave >> 1, wn = wave & 1;
#pragma unroll
  for (int i = 0; i < 4; i++)
#pragma unroll
    for (int r = 0; r < 4; r++) {
      const int l = l0 + wm * 64 + i * 16 + quad * 4 + r;
      const float inv = 1.0f / rowsum[l];
#pragma unroll
      for (int j = 0; j < 4; j++)
        Y[(long)l * DDIM + j0 + wn * 64 + j * 16 + l16] = acc[i][j][r] * inv;
    }
}

extern "C" void kernel_launch(void* const* d_in, const int* in_sizes, int n_in,
                              void* d_out, int out_size, void* d_ws, size_t ws_size,
                              hipStream_t stream) {
  const float* x  = (const float*)d_in[0];   // (4096, 2048)
  const float* Wq = (const float*)d_in[1];   // (2048, 2048)
  const float* Pk = (const float*)d_in[2];   // (1, 4096, 2048)
  const float* Pv = (const float*)d_in[3];   // (1, 4096, 2048)
  const int* wptr = (const int*)d_in[4];     // sliding_window_size
  float* Y = (float*)d_out;                  // (1, 4096, 2048) f32

  // ws (u16 elems). P aliases xb+wb (dead after K1). Total ~84 MB.
  unsigned short* base = (unsigned short*)d_ws;
  unsigned short* Pm = base;                          // 4096*4096  (33.6 MB)  [K2/K3]
  unsigned short* xb = base;                          // 4096*2048  (aliases Pm) [K0/K1]
  unsigned short* wb = base + (size_t)LDIM * DDIM;    // 2048*2048  (aliases Pm) [K0/K1]
  unsigned short* kb = base + (size_t)TDIM * TDIM;    // 4096*2048
  unsigned short* vt = kb + (size_t)TDIM * DDIM;      // 2048*4096
  unsigned short* qb = vt + (size_t)DDIM * TDIM;      // 4096*2048
  float* rowsum = (float*)(qb + (size_t)LDIM * DDIM); // 4096 f32

  hipMemsetAsync(rowsum, 0, LDIM * sizeof(float), stream);
  k_cvt<<<LDIM * DDIM / 8 / 256, 256, 0, stream>>>(x, xb, LDIM * DDIM / 8);
  k_cvt<<<DDIM * DDIM / 8 / 256, 256, 0, stream>>>(Wq, wb, DDIM * DDIM / 8);
  k_cvt<<<TDIM * DDIM / 8 / 256, 256, 0, stream>>>(Pk, kb, TDIM * DDIM / 8);
  k_trans<<<dim3(TDIM / 64, DDIM / 64), 256, 0, stream>>>(Pv, vt);
  k1_qgemm<<<dim3(DDIM / 128, LDIM / 128), 256, 0, stream>>>(xb, wb, qb);
  k2_qk<<<dim3(TDIM / 128, LDIM / 128), 256, 0, stream>>>(qb, kb, Pm, rowsum, wptr);
  k3_pv<<<dim3(DDIM / 128, LDIM / 128), 256, 0, stream>>>(Pm, vt, rowsum, Y, wptr);
}

// Round 3
// 310.494 us; speedup vs baseline: 1.6275x; 1.0274x over previous
//
#include <hip/hip_runtime.h>

// PAttention: y = softmax_band(x@Wq^T @ Pk^T * scale) @ Pv, window |l-t|<w.
// L=4096, T=4096, d=2048. Pipeline:
//   k_prep: convert x,Wq,Pk -> bf16; transpose+convert Pv -> Vt (d x T); zero rowsum
//   k1: q = x·Wq^T      (128x128 tile, BK=64, XOR-swizzled global_load_lds staging)
//   k2: P = exp(q·Pk^T·scale) band tiles + fp32 rowsums
//   k3: y = (P·Vt^T)/rowsum over band tiles
// MFMA 16x16x32 bf16 (m89/m91 layouts): A/B frag [idx=lane&15][k=(lane>>4)*8+j],
// C/D col=lane&15, row=(lane>>4)*4+reg.
// LDS swizzle: global_load_lds writes lane*16B; lane fetches col-block
// (lane&7)^(row&7), so frag read unit = row*8 + (cb^(row&7)) is bank-conflict-free.

using bf16x8 = __attribute__((ext_vector_type(8))) short;
using f32x4  = __attribute__((ext_vector_type(4))) float;

#define LDIM 4096
#define TDIM 4096
#define DDIM 2048

static __device__ __forceinline__ unsigned short f2bf(float f) {
  union { float f; unsigned u; } c; c.f = f;
  unsigned r = c.u + 0x7FFFu + ((c.u >> 16) & 1u);  // RNE
  return (unsigned short)(r >> 16);
}
static __device__ __forceinline__ unsigned pack2(float a, float b) {
  return (unsigned)f2bf(a) | ((unsigned)f2bf(b) << 16);
}
static __device__ __forceinline__ void gload16(const void* g, void* l) {
  __builtin_amdgcn_global_load_lds((const __attribute__((address_space(1))) void*)g,
                                   (__attribute__((address_space(3))) void*)l, 16, 0, 0);
}

// ---- prep: blocks [0,10240) converts, [10240,12288) Pv transpose, 12288 rowsum ----
__global__ __launch_bounds__(256) void k_prep(const float* __restrict__ x,
                                              const float* __restrict__ Wq,
                                              const float* __restrict__ Pk,
                                              const float* __restrict__ Pv,
                                              unsigned short* __restrict__ xb,
                                              unsigned short* __restrict__ wb,
                                              unsigned short* __restrict__ kb,
                                              unsigned short* __restrict__ vt,
                                              float* __restrict__ rowsum) {
  const int tid = threadIdx.x;
  const int b = blockIdx.x;
  if (b < 10240) {  // elementwise f32 -> bf16, 8 elems/thread
    const float* in; unsigned short* out; size_t i;
    if (b < 4096)      { in = x;  out = xb; i = (size_t)b * 256 + tid; }
    else if (b < 6144) { in = Wq; out = wb; i = (size_t)(b - 4096) * 256 + tid; }
    else               { in = Pk; out = kb; i = (size_t)(b - 6144) * 256 + tid; }
    const float4* p = (const float4*)(in + i * 8);
    float4 a = p[0], c = p[1];
    uint4 o = { pack2(a.x, a.y), pack2(a.z, a.w), pack2(c.x, c.y), pack2(c.z, c.w) };
    *(uint4*)(out + i * 8) = o;
    return;
  }
  if (b == 12288) {
    for (int k = tid; k < LDIM; k += 256) rowsum[k] = 0.f;
    return;
  }
  // Pv (T x D) f32 -> Vt (D x T) bf16, 64x64 tile, transpose in LDS
  __shared__ unsigned short tile[64][72];  // [j_local][t_local], padded
  const int b2 = b - 10240;
  const int t0 = (b2 & 63) * 64, j0 = (b2 >> 6) * 64;
  const int r = tid >> 4, c4 = (tid & 15) * 4;
#pragma unroll
  for (int rr = 0; rr < 64; rr += 16) {
    float4 v = *(const float4*)(Pv + (size_t)(t0 + r + rr) * DDIM + j0 + c4);
    tile[c4 + 0][r + rr] = f2bf(v.x);
    tile[c4 + 1][r + rr] = f2bf(v.y);
    tile[c4 + 2][r + rr] = f2bf(v.z);
    tile[c4 + 3][r + rr] = f2bf(v.w);
  }
  __syncthreads();
  const int jr = tid >> 3, tc = (tid & 7) * 8;
#pragma unroll
  for (int jj = 0; jj < 64; jj += 32)
    *(uint4*)(vt + (size_t)(j0 + jr + jj) * TDIM + t0 + tc) =
        *(const uint4*)&tile[jr + jj][tc];
}

// ------- shared 128x128, BK=64, swizzled-staging bf16 GEMM K-loop -------
static __device__ __forceinline__ void gemm_loop(const unsigned short* __restrict__ A,
                                                 const unsigned short* __restrict__ B,
                                                 int m0, int n0, long lda, long ldb,
                                                 int kbeg, int kend,
                                                 unsigned short* As, unsigned short* Bs,
                                                 f32x4 (&acc)[4][4]) {
  const int tid = threadIdx.x;
  const int wave = tid >> 6, lane = tid & 63;
  const int quad = lane >> 4, l16 = lane & 15;
  const int wm = wave >> 1, wn = wave & 1;
  // staging unit u = c*256 + wave*64 + lane -> row = u>>3, swizzled cb = (u&7)^(row&7)
  const int srow = tid >> 3;                 // chunk c adds 32 (row&7 invariant)
  const int scb = (tid & 7) ^ (srow & 7);
  const int fr = l16 & 7;

  const unsigned short* gA = A + (long)(m0 + srow) * lda + scb * 8;
  const unsigned short* gB = B + (long)(n0 + srow) * ldb + scb * 8;
  unsigned short* lA = As + wave * 512;  // u16 units; + c*2048
  unsigned short* lB = Bs + wave * 512;

  for (int k0 = kbeg; k0 < kend; k0 += 64) {
#pragma unroll
    for (int c = 0; c < 4; c++) {
      gload16(gA + (long)c * 32 * lda + k0, lA + c * 2048);
      gload16(gB + (long)c * 32 * ldb + k0, lB + c * 2048);
    }
    __syncthreads();
#pragma unroll
    for (int s = 0; s < 2; s++) {
      bf16x8 af[4], bfr[4];
#pragma unroll
      for (int i = 0; i < 4; i++)
        af[i] = *(const bf16x8*)&As[((wm * 64 + i * 16 + l16) * 8 + ((s * 4 + quad) ^ fr)) * 8];
#pragma unroll
      for (int j = 0; j < 4; j++)
        bfr[j] = *(const bf16x8*)&Bs[((wn * 64 + j * 16 + l16) * 8 + ((s * 4 + quad) ^ fr)) * 8];
#pragma unroll
      for (int i = 0; i < 4; i++)
#pragma unroll
        for (int j = 0; j < 4; j++)
          acc[i][j] = __builtin_amdgcn_mfma_f32_16x16x32_bf16(af[i], bfr[j], acc[i][j], 0, 0, 0);
    }
    __syncthreads();
  }
}

// ---------------- K1: q = x · Wq^T  (bf16 out) ----------------
__global__ __launch_bounds__(256) void k1_qgemm(const unsigned short* __restrict__ X,
                                                const unsigned short* __restrict__ W,
                                                unsigned short* __restrict__ q) {
  __shared__ __align__(16) unsigned short As[128 * 64];
  __shared__ __align__(16) unsigned short Bs[128 * 64];
  f32x4 acc[4][4] = {};
  const int m0 = blockIdx.y * 128, n0 = blockIdx.x * 128;
  gemm_loop(X, W, m0, n0, DDIM, DDIM, 0, DDIM, As, Bs, acc);
  const int tid = threadIdx.x;
  const int wave = tid >> 6, lane = tid & 63;
  const int quad = lane >> 4, l16 = lane & 15, wm = wave >> 1, wn = wave & 1;
#pragma unroll
  for (int i = 0; i < 4; i++)
#pragma unroll
    for (int j = 0; j < 4; j++)
#pragma unroll
      for (int r = 0; r < 4; r++) {
        int row = m0 + wm * 64 + i * 16 + quad * 4 + r;
        int col = n0 + wn * 64 + j * 16 + l16;
        q[(long)row * DDIM + col] = f2bf(acc[i][j][r]);
      }
}

// ------------- K2: banded P = exp(q·Pk^T·scale), rowsums -------------
__global__ __launch_bounds__(256) void k2_qk(const unsigned short* __restrict__ Q,
                                             const unsigned short* __restrict__ Kb,
                                             unsigned short* __restrict__ P,
                                             float* __restrict__ rowsum,
                                             const int* __restrict__ wptr) {
  const int w = *wptr;
  const int l0 = blockIdx.y * 128, t0 = blockIdx.x * 128;
  int lo = l0 - w + 1; if (lo < 0) lo = 0;
  int hi = l0 + 127 + w - 1; if (hi > TDIM - 1) hi = TDIM - 1;
  if ((int)blockIdx.x < (lo >> 7) || (int)blockIdx.x > (hi >> 7)) return;  // uniform
  __shared__ __align__(16) unsigned short As[128 * 64];
  __shared__ __align__(16) unsigned short Bs[128 * 64];
  f32x4 acc[4][4] = {};
  gemm_loop(Q, Kb, l0, t0, DDIM, DDIM, 0, DDIM, As, Bs, acc);
  const float scale = 0.022097086912079608f;  // 1/sqrt(2048)
  const int tid = threadIdx.x;
  const int wave = tid >> 6, lane = tid & 63;
  const int quad = lane >> 4, l16 = lane & 15, wm = wave >> 1, wn = wave & 1;
#pragma unroll
  for (int i = 0; i < 4; i++) {
    float rs[4] = {0.f, 0.f, 0.f, 0.f};
#pragma unroll
    for (int j = 0; j < 4; j++)
#pragma unroll
      for (int r = 0; r < 4; r++) {
        int l = l0 + wm * 64 + i * 16 + quad * 4 + r;
        int t = t0 + wn * 64 + j * 16 + l16;
        int dlt = l - t; dlt = dlt < 0 ? -dlt : dlt;
        float e = 0.f;
        // scores ~ N(0,1): no overflow -> max-free softmax is exact math
        if (dlt < w) e = __expf(acc[i][j][r] * scale);
        unsigned short bv = f2bf(e);
        P[(long)l * TDIM + t] = bv;
        rs[r] += __uint_as_float((unsigned)bv << 16);  // sum stored (rounded) values
      }
#pragma unroll
    for (int r = 0; r < 4; ++r) {
      float s = rs[r];
      s += __shfl_xor(s, 1);
      s += __shfl_xor(s, 2);
      s += __shfl_xor(s, 4);
      s += __shfl_xor(s, 8);  // 16 lanes hold this row
      if (l16 == 0) atomicAdd(&rowsum[l0 + wm * 64 + i * 16 + quad * 4 + r], s);
    }
  }
}

// ---------------- K3: y = (P · Vt^T) / rowsum over band tiles ----------------
__global__ __launch_bounds__(256) void k3_pv(const unsigned short* __restrict__ P,
                                             const unsigned short* __restrict__ Vt,
                                             const float* __restrict__ rowsum,
                                             float* __restrict__ Y,
                                             const int* __restrict__ wptr) {
  const int w = *wptr;
  const int l0 = blockIdx.y * 128, j0 = blockIdx.x * 128;
  int lo = l0 - w + 1; if (lo < 0) lo = 0;
  int hi = l0 + 127 + w - 1; if (hi > TDIM - 1) hi = TDIM - 1;
  const int kb = (lo >> 7) * 128, ke = ((hi >> 7) + 1) * 128;  // exactly K2's tiles
  __shared__ __align__(16) unsigned short As[128 * 64];
  __shared__ __align__(16) unsigned short Bs[128 * 64];
  f32x4 acc[4][4] = {};
  gemm_loop(P, Vt, l0, j0, TDIM, TDIM, kb, ke, As, Bs, acc);
  const int tid = threadIdx.x;
  const int wave = tid >> 6, lane = tid & 63;
  const int quad = lane >> 4, l16 = lane & 15, wm = wave >> 1, wn = wave & 1;
#pragma unroll
  for (int i = 0; i < 4; i++)
#pragma unroll
    for (int r = 0; r < 4; r++) {
      const int l = l0 + wm * 64 + i * 16 + quad * 4 + r;
      const float inv = 1.0f / rowsum[l];
#pragma unroll
      for (int j = 0; j < 4; j++)
        Y[(long)l * DDIM + j0 + wn * 64 + j * 16 + l16] = acc[i][j][r] * inv;
    }
}

extern "C" void kernel_launch(void* const* d_in, const int* in_sizes, int n_in,
                              void* d_out, int out_size, void* d_ws, size_t ws_size,
                              hipStream_t stream) {
  const float* x  = (const float*)d_in[0];   // (4096, 2048)
  const float* Wq = (const float*)d_in[1];   // (2048, 2048)
  const float* Pk = (const float*)d_in[2];   // (1, 4096, 2048)
  const float* Pv = (const float*)d_in[3];   // (1, 4096, 2048)
  const int* wptr = (const int*)d_in[4];     // sliding_window_size
  float* Y = (float*)d_out;                  // (1, 4096, 2048) f32

  // ws (u16 elems). P aliases xb+wb (dead after K1). Total ~84 MB.
  unsigned short* base = (unsigned short*)d_ws;
  unsigned short* Pm = base;                          // 4096*4096 [k2/k3]
  unsigned short* xb = base;                          // 4096*2048 (aliases Pm)
  unsigned short* wb = base + (size_t)LDIM * DDIM;    // 2048*2048 (aliases Pm)
  unsigned short* kb = base + (size_t)TDIM * TDIM;    // 4096*2048
  unsigned short* vt = kb + (size_t)TDIM * DDIM;      // 2048*4096
  unsigned short* qb = vt + (size_t)DDIM * TDIM;      // 4096*2048
  float* rowsum = (float*)(qb + (size_t)LDIM * DDIM); // 4096 f32

  k_prep<<<12289, 256, 0, stream>>>(x, Wq, Pk, Pv, xb, wb, kb, vt, rowsum);
  k1_qgemm<<<dim3(DDIM / 128, LDIM / 128), 256, 0, stream>>>(xb, wb, qb);
  k2_qk<<<dim3(TDIM / 128, LDIM / 128), 256, 0, stream>>>(qb, kb, Pm, rowsum, wptr);
  k3_pv<<<dim3(DDIM / 128, LDIM / 128), 256, 0, stream>>>(Pm, vt, rowsum, Y, wptr);
}

// Round 4
// 308.634 us; speedup vs baseline: 1.6373x; 1.0060x over previous
//
#include <hip/hip_runtime.h>

// PAttention: y = softmax_band(x@Wq^T @ Pk^T * scale) @ Pv, window |l-t|<w.
// L=4096, T=4096, d=2048. Pipeline:
//   k_prep: convert x,Wq,Pk -> bf16; transpose+convert Pv -> Vt (d x T); zero rowsum
//   k1: q = x·Wq^T      (128x128 tile, BK=32, swizzled global_load_lds staging)
//   k2: P = exp(q·Pk^T·scale) band tiles + fp32 rowsums
//   k3: y = (P·Vt^T)/rowsum over band tiles
// MFMA 16x16x32 bf16 (m89/m91 layouts): A/B frag [idx=lane&15][k=(lane>>4)*8+j],
// C/D col=lane&15, row=(lane>>4)*4+reg.
// Staging (BK=32, 4 DMA loads/thread — R3 lesson: 8 loads/thread stalled the
// DMA queue): wave w stages rows [w*32, w*32+32), lane -> row w*32+(lane>>2),
// col-block swizzled by (lane>>4)&3 so the frag ds_read_b128 (row stride 64B,
// bank0 = (l16&1)*16 + unit*4) lands 2 lanes/bank-pair = conflict-free (m136).

using bf16x8 = __attribute__((ext_vector_type(8))) short;
using f32x4  = __attribute__((ext_vector_type(4))) float;

#define LDIM 4096
#define TDIM 4096
#define DDIM 2048

static __device__ __forceinline__ unsigned short f2bf(float f) {
  union { float f; unsigned u; } c; c.f = f;
  unsigned r = c.u + 0x7FFFu + ((c.u >> 16) & 1u);  // RNE
  return (unsigned short)(r >> 16);
}
static __device__ __forceinline__ unsigned pack2(float a, float b) {
  return (unsigned)f2bf(a) | ((unsigned)f2bf(b) << 16);
}
static __device__ __forceinline__ void gload16(const void* g, void* l) {
  __builtin_amdgcn_global_load_lds((const __attribute__((address_space(1))) void*)g,
                                   (__attribute__((address_space(3))) void*)l, 16, 0, 0);
}

// ---- prep: blocks [0,10240) converts, [10240,12288) Pv transpose, 12288 rowsum ----
__global__ __launch_bounds__(256) void k_prep(const float* __restrict__ x,
                                              const float* __restrict__ Wq,
                                              const float* __restrict__ Pk,
                                              const float* __restrict__ Pv,
                                              unsigned short* __restrict__ xb,
                                              unsigned short* __restrict__ wb,
                                              unsigned short* __restrict__ kb,
                                              unsigned short* __restrict__ vt,
                                              float* __restrict__ rowsum) {
  const int tid = threadIdx.x;
  const int b = blockIdx.x;
  if (b < 10240) {  // elementwise f32 -> bf16, 8 elems/thread
    const float* in; unsigned short* out; size_t i;
    if (b < 4096)      { in = x;  out = xb; i = (size_t)b * 256 + tid; }
    else if (b < 6144) { in = Wq; out = wb; i = (size_t)(b - 4096) * 256 + tid; }
    else               { in = Pk; out = kb; i = (size_t)(b - 6144) * 256 + tid; }
    const float4* p = (const float4*)(in + i * 8);
    float4 a = p[0], c = p[1];
    uint4 o = { pack2(a.x, a.y), pack2(a.z, a.w), pack2(c.x, c.y), pack2(c.z, c.w) };
    *(uint4*)(out + i * 8) = o;
    return;
  }
  if (b == 12288) {
    for (int k = tid; k < LDIM; k += 256) rowsum[k] = 0.f;
    return;
  }
  // Pv (T x D) f32 -> Vt (D x T) bf16, 64x64 tile, transpose in LDS
  __shared__ unsigned short tile[64][72];  // [j_local][t_local], padded
  const int b2 = b - 10240;
  const int t0 = (b2 & 63) * 64, j0 = (b2 >> 6) * 64;
  const int r = tid >> 4, c4 = (tid & 15) * 4;
#pragma unroll
  for (int rr = 0; rr < 64; rr += 16) {
    float4 v = *(const float4*)(Pv + (size_t)(t0 + r + rr) * DDIM + j0 + c4);
    tile[c4 + 0][r + rr] = f2bf(v.x);
    tile[c4 + 1][r + rr] = f2bf(v.y);
    tile[c4 + 2][r + rr] = f2bf(v.z);
    tile[c4 + 3][r + rr] = f2bf(v.w);
  }
  __syncthreads();
  const int jr = tid >> 3, tc = (tid & 7) * 8;
#pragma unroll
  for (int jj = 0; jj < 64; jj += 32)
    *(uint4*)(vt + (size_t)(j0 + jr + jj) * TDIM + t0 + tc) =
        *(const uint4*)&tile[jr + jj][tc];
}

// ------- shared 128x128, BK=32, swizzled wave-local staging bf16 GEMM K-loop -------
static __device__ __forceinline__ void gemm_loop(const unsigned short* __restrict__ A,
                                                 const unsigned short* __restrict__ B,
                                                 int m0, int n0, long lda, long ldb,
                                                 int kbeg, int kend,
                                                 unsigned short* As, unsigned short* Bs,
                                                 f32x4 (&acc)[4][4]) {
  const int tid = threadIdx.x;
  const int wave = tid >> 6, lane = tid & 63;
  const int quad = lane >> 4, l16 = lane & 15;
  const int wm = wave >> 1, wn = wave & 1;
  const int srow = wave * 32 + (lane >> 2);          // wave-local rows
  const int scb  = (lane & 3) ^ ((lane >> 4) & 3);   // swizzled source col-block
  const int fu   = (l16 >> 2) & 3;                   // frag-read unit XOR

  const unsigned short* gA = A + (long)(m0 + srow) * lda + scb * 8;
  const unsigned short* gB = B + (long)(n0 + srow) * ldb + scb * 8;
  unsigned short* lA = As + wave * 1024;  // u16 units
  unsigned short* lB = Bs + wave * 1024;

  for (int k0 = kbeg; k0 < kend; k0 += 32) {
    gload16(gA + k0,            lA);
    gload16(gA + k0 + 16 * lda, lA + 512);
    gload16(gB + k0,            lB);
    gload16(gB + k0 + 16 * ldb, lB + 512);
    __syncthreads();
    bf16x8 af[4], bfr[4];
#pragma unroll
    for (int i = 0; i < 4; i++)
      af[i] = *(const bf16x8*)&As[(wm * 64 + i * 16 + l16) * 32 + ((quad ^ fu) * 8)];
#pragma unroll
    for (int j = 0; j < 4; j++)
      bfr[j] = *(const bf16x8*)&Bs[(wn * 64 + j * 16 + l16) * 32 + ((quad ^ fu) * 8)];
#pragma unroll
    for (int i = 0; i < 4; i++)
#pragma unroll
      for (int j = 0; j < 4; j++)
        acc[i][j] = __builtin_amdgcn_mfma_f32_16x16x32_bf16(af[i], bfr[j], acc[i][j], 0, 0, 0);
    __syncthreads();
  }
}

// ---------------- K1: q = x · Wq^T  (bf16 out) ----------------
__global__ __launch_bounds__(256) void k1_qgemm(const unsigned short* __restrict__ X,
                                                const unsigned short* __restrict__ W,
                                                unsigned short* __restrict__ q) {
  __shared__ __align__(16) unsigned short As[128 * 32];
  __shared__ __align__(16) unsigned short Bs[128 * 32];
  f32x4 acc[4][4] = {};
  const int m0 = blockIdx.y * 128, n0 = blockIdx.x * 128;
  gemm_loop(X, W, m0, n0, DDIM, DDIM, 0, DDIM, As, Bs, acc);
  const int tid = threadIdx.x;
  const int wave = tid >> 6, lane = tid & 63;
  const int quad = lane >> 4, l16 = lane & 15, wm = wave >> 1, wn = wave & 1;
#pragma unroll
  for (int i = 0; i < 4; i++)
#pragma unroll
    for (int j = 0; j < 4; j++)
#pragma unroll
      for (int r = 0; r < 4; r++) {
        int row = m0 + wm * 64 + i * 16 + quad * 4 + r;
        int col = n0 + wn * 64 + j * 16 + l16;
        q[(long)row * DDIM + col] = f2bf(acc[i][j][r]);
      }
}

// ------------- K2: banded P = exp(q·Pk^T·scale), rowsums -------------
__global__ __launch_bounds__(256) void k2_qk(const unsigned short* __restrict__ Q,
                                             const unsigned short* __restrict__ Kb,
                                             unsigned short* __restrict__ P,
                                             float* __restrict__ rowsum,
                                             const int* __restrict__ wptr) {
  const int w = *wptr;
  const int l0 = blockIdx.y * 128, t0 = blockIdx.x * 128;
  int lo = l0 - w + 1; if (lo < 0) lo = 0;
  int hi = l0 + 127 + w - 1; if (hi > TDIM - 1) hi = TDIM - 1;
  if ((int)blockIdx.x < (lo >> 7) || (int)blockIdx.x > (hi >> 7)) return;  // uniform
  __shared__ __align__(16) unsigned short As[128 * 32];
  __shared__ __align__(16) unsigned short Bs[128 * 32];
  f32x4 acc[4][4] = {};
  gemm_loop(Q, Kb, l0, t0, DDIM, DDIM, 0, DDIM, As, Bs, acc);
  const float scale = 0.022097086912079608f;  // 1/sqrt(2048)
  const int tid = threadIdx.x;
  const int wave = tid >> 6, lane = tid & 63;
  const int quad = lane >> 4, l16 = lane & 15, wm = wave >> 1, wn = wave & 1;
#pragma unroll
  for (int i = 0; i < 4; i++) {
    float rs[4] = {0.f, 0.f, 0.f, 0.f};
#pragma unroll
    for (int j = 0; j < 4; j++)
#pragma unroll
      for (int r = 0; r < 4; r++) {
        int l = l0 + wm * 64 + i * 16 + quad * 4 + r;
        int t = t0 + wn * 64 + j * 16 + l16;
        int dlt = l - t; dlt = dlt < 0 ? -dlt : dlt;
        float e = 0.f;
        // scores ~ N(0,1): no overflow -> max-free softmax is exact math
        if (dlt < w) e = __expf(acc[i][j][r] * scale);
        unsigned short bv = f2bf(e);
        P[(long)l * TDIM + t] = bv;
        rs[r] += __uint_as_float((unsigned)bv << 16);  // sum stored (rounded) values
      }
#pragma unroll
    for (int r = 0; r < 4; ++r) {
      float s = rs[r];
      s += __shfl_xor(s, 1);
      s += __shfl_xor(s, 2);
      s += __shfl_xor(s, 4);
      s += __shfl_xor(s, 8);  // 16 lanes hold this row
      if (l16 == 0) atomicAdd(&rowsum[l0 + wm * 64 + i * 16 + quad * 4 + r], s);
    }
  }
}

// ---------------- K3: y = (P · Vt^T) / rowsum over band tiles ----------------
__global__ __launch_bounds__(256) void k3_pv(const unsigned short* __restrict__ P,
                                             const unsigned short* __restrict__ Vt,
                                             const float* __restrict__ rowsum,
                                             float* __restrict__ Y,
                                             const int* __restrict__ wptr) {
  const int w = *wptr;
  const int l0 = blockIdx.y * 128, j0 = blockIdx.x * 128;
  int lo = l0 - w + 1; if (lo < 0) lo = 0;
  int hi = l0 + 127 + w - 1; if (hi > TDIM - 1) hi = TDIM - 1;
  const int kb = (lo >> 7) * 128, ke = ((hi >> 7) + 1) * 128;  // exactly K2's tiles
  __shared__ __align__(16) unsigned short As[128 * 32];
  __shared__ __align__(16) unsigned short Bs[128 * 32];
  f32x4 acc[4][4] = {};
  gemm_loop(P, Vt, l0, j0, TDIM, TDIM, kb, ke, As, Bs, acc);
  const int tid = threadIdx.x;
  const int wave = tid >> 6, lane = tid & 63;
  const int quad = lane >> 4, l16 = lane & 15, wm = wave >> 1, wn = wave & 1;
#pragma unroll
  for (int i = 0; i < 4; i++)
#pragma unroll
    for (int r = 0; r < 4; r++) {
      const int l = l0 + wm * 64 + i * 16 + quad * 4 + r;
      const float inv = 1.0f / rowsum[l];
#pragma unroll
      for (int j = 0; j < 4; j++)
        Y[(long)l * DDIM + j0 + wn * 64 + j * 16 + l16] = acc[i][j][r] * inv;
    }
}

extern "C" void kernel_launch(void* const* d_in, const int* in_sizes, int n_in,
                              void* d_out, int out_size, void* d_ws, size_t ws_size,
                              hipStream_t stream) {
  const float* x  = (const float*)d_in[0];   // (4096, 2048)
  const float* Wq = (const float*)d_in[1];   // (2048, 2048)
  const float* Pk = (const float*)d_in[2];   // (1, 4096, 2048)
  const float* Pv = (const float*)d_in[3];   // (1, 4096, 2048)
  const int* wptr = (const int*)d_in[4];     // sliding_window_size
  float* Y = (float*)d_out;                  // (1, 4096, 2048) f32

  // ws (u16 elems). P aliases xb+wb (dead after K1). Total ~84 MB.
  unsigned short* base = (unsigned short*)d_ws;
  unsigned short* Pm = base;                          // 4096*4096 [k2/k3]
  unsigned short* xb = base;                          // 4096*2048 (aliases Pm)
  unsigned short* wb = base + (size_t)LDIM * DDIM;    // 2048*2048 (aliases Pm)
  unsigned short* kb = base + (size_t)TDIM * TDIM;    // 4096*2048
  unsigned short* vt = kb + (size_t)TDIM * DDIM;      // 2048*4096
  unsigned short* qb = vt + (size_t)DDIM * TDIM;      // 4096*2048
  float* rowsum = (float*)(qb + (size_t)LDIM * DDIM); // 4096 f32

  k_prep<<<12289, 256, 0, stream>>>(x, Wq, Pk, Pv, xb, wb, kb, vt, rowsum);
  k1_qgemm<<<dim3(DDIM / 128, LDIM / 128), 256, 0, stream>>>(xb, wb, qb);
  k2_qk<<<dim3(TDIM / 128, LDIM / 128), 256, 0, stream>>>(qb, kb, Pm, rowsum, wptr);
  k3_pv<<<dim3(DDIM / 128, LDIM / 128), 256, 0, stream>>>(Pm, vt, rowsum, Y, wptr);
}